// Round 10
// baseline (246.649 us; speedup 1.0000x reference)
//
#include <hip/hip_runtime.h>
#include <cmath>

#define BQ 300
#define DIM 256
#define NH 8
#define HD 32
#define NB 32
#define MROWS 9600
#define SENC 8400

typedef unsigned short ushort_t;
typedef __attribute__((ext_vector_type(8))) short short8;
typedef __attribute__((ext_vector_type(4))) float f32x4;
typedef __attribute__((ext_vector_type(4))) unsigned short us4;
typedef __attribute__((address_space(1))) unsigned int ga_u32;
typedef __attribute__((address_space(3))) unsigned int ls_u32;

__device__ __forceinline__ float bf2f(ushort_t u) {
    union { unsigned u32; float f; } x; x.u32 = ((unsigned)u) << 16; return x.f;
}
__device__ __forceinline__ ushort_t f2bf(float f) {
    union { float f; unsigned u; } x; x.f = f;
    unsigned u = x.u;
    u += 0x7fffu + ((u >> 16) & 1u);
    return (ushort_t)(u >> 16);
}

// ---------------- prep: activation cvt (single pass) + weight transposes ----------------
__global__ __launch_bounds__(256)
void prep_all(const float* __restrict__ hidden, const float* __restrict__ pos,
              ushort_t* __restrict__ hq, ushort_t* __restrict__ hid,
              const float* __restrict__ q_w, const float* __restrict__ k_w,
              const float* __restrict__ v_w, const float* __restrict__ o_w,
              const float* __restrict__ off_w, const float* __restrict__ aw_w,
              const float* __restrict__ gate_w, const float* __restrict__ fc1_w,
              const float* __restrict__ fc2_w,
              ushort_t* __restrict__ qkvT, ushort_t* __restrict__ oT,
              ushort_t* __restrict__ offawT, ushort_t* __restrict__ gT,
              ushort_t* __restrict__ f1T, ushort_t* __restrict__ f2T,
              const float* __restrict__ q_b, const float* __restrict__ k_b,
              const float* __restrict__ v_b, float* __restrict__ qkvb,
              float scal)
{
    const int tid = threadIdx.x;
    if (blockIdx.x < 2400) {
        int i = blockIdx.x * 256 + tid;   // 0 .. 614399 float4s
        float4 a = ((const float4*)hidden)[i];
        float4 b = ((const float4*)pos)[i];
        us4 uq, uh;
        uq.x = f2bf(a.x + b.x); uq.y = f2bf(a.y + b.y);
        uq.z = f2bf(a.z + b.z); uq.w = f2bf(a.w + b.w);
        uh.x = f2bf(a.x); uh.y = f2bf(a.y); uh.z = f2bf(a.z); uh.w = f2bf(a.w);
        *(us4*)&hq[(size_t)i * 4] = uq;
        *(us4*)&hid[(size_t)i * 4] = uh;
        return;
    }
    __shared__ float t[32][33];
    const int bid = blockIdx.x - 2400;
    const float* src; ushort_t* dst; int K, N, local; float scale = 1.0f;

    if (bid < 64)       { src = q_w;   dst = qkvT;             K = 256; N = 256;  local = bid;       scale = scal; }
    else if (bid < 128) { src = k_w;   dst = qkvT + 256 * 256; K = 256; N = 256;  local = bid - 64; }
    else if (bid < 192) { src = v_w;   dst = qkvT + 512 * 256; K = 256; N = 256;  local = bid - 128; }
    else if (bid < 256) { src = o_w;   dst = oT;               K = 256; N = 256;  local = bid - 192; }
    else if (bid < 304) { src = off_w; dst = offawT;           K = 256; N = 192;  local = bid - 256; }
    else if (bid < 328) { src = aw_w;  dst = offawT + 192 * 256; K = 256; N = 96; local = bid - 304; }
    else if (bid < 336) {   // zero-fill offawT rows 288..319
        int l = bid - 328;
        ushort_t* d2 = offawT + 288 * 256 + l * 32;
        for (int e = tid; e < 32 * 32; e += 256) { int r = e >> 5, c = e & 31; d2[r * 256 + c] = 0; }
        return;
    }
    else if (bid < 592) { src = gate_w; dst = gT;  K = 512;  N = 512;  local = bid - 336; }
    else if (bid < 848) { src = fc1_w;  dst = f1T; K = 256;  N = 1024; local = bid - 592; }
    else if (bid < 1104){ src = fc2_w;  dst = f2T; K = 1024; N = 256;  local = bid - 848; }
    else {  // combined qkv bias (q scaled)
        #pragma unroll
        for (int j = 0; j < 3; ++j) {
            int c = j * 256 + tid;
            float v = (j == 0) ? q_b[tid] * scal : (j == 1) ? k_b[tid] : v_b[tid];
            qkvb[c] = v;
        }
        return;
    }
    const int tilesx = N >> 5;
    const int n0 = (local % tilesx) * 32, k0 = (local / tilesx) * 32;
    const int tx = tid & 31, ty = tid >> 5;
    #pragma unroll
    for (int i = 0; i < 4; ++i)
        t[ty + i * 8][tx] = src[(size_t)(k0 + ty + i * 8) * N + n0 + tx];
    __syncthreads();
    #pragma unroll
    for (int i = 0; i < 4; ++i)
        dst[(size_t)(n0 + ty + i * 8) * K + k0 + tx] = f2bf(t[tx][ty + i * 8] * scale);
}

// ---------------- MFMA GEMM (global_load_lds staging, linear LDS) ----------------
template<int BM, int BN, int ACT, bool OBF>
__global__ __launch_bounds__(256)
void gemm_mfma(const ushort_t* __restrict__ A1, const ushort_t* __restrict__ A2,
               int asplit, int lda,
               const ushort_t* __restrict__ Bt, int K,
               const float* __restrict__ bias, const float* __restrict__ bias2,
               int bsplit, int N,
               float* __restrict__ Cf, ushort_t* __restrict__ Cb, int ldc)
{
    __shared__ ushort_t As[BM * 32];
    __shared__ ushort_t Bs[BN * 32];
    const int tid = threadIdx.x;
    const int row0 = blockIdx.y * BM, col0 = blockIdx.x * BN;
    const ushort_t* __restrict__ A = (col0 < asplit) ? A1 : A2;
    const int lane = tid & 63, wid = tid >> 6;
    const int wm = wid >> 1, wn = wid & 1;
    constexpr int FM = BM / 32, FN = BN / 32;
    const int r16 = lane & 15, kg = lane >> 4;
    const int rsub = lane >> 2, c8 = (lane & 3) * 8;   // staging lane map: 4 lanes/row

    f32x4 acc[FM][FN];
    #pragma unroll
    for (int m = 0; m < FM; ++m)
        #pragma unroll
        for (int n = 0; n < FN; ++n) {
            f32x4 z = {0.f, 0.f, 0.f, 0.f};
            acc[m][n] = z;
        }

    for (int k0 = 0; k0 < K; k0 += 32) {
        #pragma unroll
        for (int i = wid; i < BM / 16; i += 4) {
            const int r = i * 16 + rsub;
            __builtin_amdgcn_global_load_lds(
                (const ga_u32*)(const void*)&A[(size_t)(row0 + r) * lda + k0 + c8],
                (ls_u32*)(void*)&As[i * 512], 16, 0, 0);
        }
        #pragma unroll
        for (int i = wid; i < BN / 16; i += 4) {
            const int r = i * 16 + rsub;
            __builtin_amdgcn_global_load_lds(
                (const ga_u32*)(const void*)&Bt[(size_t)(col0 + r) * K + k0 + c8],
                (ls_u32*)(void*)&Bs[i * 512], 16, 0, 0);
        }
        __syncthreads();
        short8 a[FM], b[FN];
        #pragma unroll
        for (int m = 0; m < FM; ++m)
            a[m] = *(const short8*)&As[(wm * (BM / 2) + m * 16 + r16) * 32 + kg * 8];
        #pragma unroll
        for (int n = 0; n < FN; ++n)
            b[n] = *(const short8*)&Bs[(wn * (BN / 2) + n * 16 + r16) * 32 + kg * 8];
        #pragma unroll
        for (int m = 0; m < FM; ++m)
            #pragma unroll
            for (int n = 0; n < FN; ++n)
                acc[m][n] = __builtin_amdgcn_mfma_f32_16x16x32_bf16(a[m], b[n], acc[m][n], 0, 0, 0);
        __syncthreads();
    }

    #pragma unroll
    for (int m = 0; m < FM; ++m) {
        #pragma unroll
        for (int n = 0; n < FN; ++n) {
            int colb = col0 + wn * (BN / 2) + n * 16 + r16;
            float bs;
            if (colb < bsplit) bs = bias[colb];
            else if (colb < N) bs = bias2[colb - bsplit];
            else bs = 0.0f;
            #pragma unroll
            for (int r = 0; r < 4; ++r) {
                int row = row0 + wm * (BM / 2) + m * 16 + kg * 4 + r;
                float v = acc[m][n][r] + bs;
                if (ACT == 1) v = fmaxf(v, 0.0f);
                if (ACT == 2) v = 1.0f / (1.0f + __expf(-v));
                if (OBF) Cb[(size_t)row * ldc + colb] = f2bf(v);
                else     Cf[(size_t)row * ldc + colb] = v;
            }
        }
    }
}

// ---------------- fused GEMM + row-LayerNorm ----------------
__global__ __launch_bounds__(256)
void gemm_ln(const ushort_t* __restrict__ A, int lda,
             const ushort_t* __restrict__ Bt, int K,
             const float* __restrict__ gb, const float* __restrict__ Y,
             const float* __restrict__ lnw, const float* __restrict__ lnb,
             float* __restrict__ outf, ushort_t* __restrict__ outbf, int ldout)
{
    constexpr int LDT = 40;
    __shared__ ushort_t As[32 * LDT];
    __shared__ ushort_t Bs[256 * LDT];
    __shared__ float sred[2][32], qred[2][32];
    const int tid = threadIdx.x;
    const int row0 = blockIdx.x * 32;
    const int lane = tid & 63, wid = tid >> 6;
    const int wm = wid >> 1, wn = wid & 1;
    const int r16 = lane & 15, kg = lane >> 4;

    f32x4 acc[8];
    #pragma unroll
    for (int n = 0; n < 8; ++n) { f32x4 z = {0.f,0.f,0.f,0.f}; acc[n] = z; }

    for (int k0 = 0; k0 < K; k0 += 32) {
        if (tid < 128) {
            int r = tid >> 2, cc = tid & 3;
            *(short8*)&As[r * LDT + cc * 8] =
                *(const short8*)&A[(size_t)(row0 + r) * lda + k0 + cc * 8];
        }
        #pragma unroll
        for (int c = 0; c < 4; ++c) {
            int idx = tid + c * 256;
            int r = idx >> 2, cc = idx & 3;
            *(short8*)&Bs[r * LDT + cc * 8] =
                *(const short8*)&Bt[(size_t)r * K + k0 + cc * 8];
        }
        __syncthreads();
        short8 a = *(const short8*)&As[(wm * 16 + r16) * LDT + kg * 8];
        #pragma unroll
        for (int n = 0; n < 8; ++n) {
            short8 b = *(const short8*)&Bs[(wn * 128 + n * 16 + r16) * LDT + kg * 8];
            acc[n] = __builtin_amdgcn_mfma_f32_16x16x32_bf16(a, b, acc[n], 0, 0, 0);
        }
        __syncthreads();
    }

    float s[4] = {0.f, 0.f, 0.f, 0.f}, q[4] = {0.f, 0.f, 0.f, 0.f};
    #pragma unroll
    for (int n = 0; n < 8; ++n) {
        const int col = wn * 128 + n * 16 + r16;
        const float gbv = gb[col];
        #pragma unroll
        for (int r = 0; r < 4; ++r) {
            const int row = row0 + wm * 16 + kg * 4 + r;
            float t = acc[n][r] + gbv + Y[(size_t)row * 256 + col];
            acc[n][r] = t;
            s[r] += t; q[r] += t * t;
        }
    }
    #pragma unroll
    for (int off = 1; off < 16; off <<= 1) {
        #pragma unroll
        for (int r = 0; r < 4; ++r) {
            s[r] += __shfl_xor(s[r], off);
            q[r] += __shfl_xor(q[r], off);
        }
    }
    if (r16 == 0) {
        #pragma unroll
        for (int r = 0; r < 4; ++r) {
            sred[wn][wm * 16 + kg * 4 + r] = s[r];
            qred[wn][wm * 16 + kg * 4 + r] = q[r];
        }
    }
    __syncthreads();
    float mn[4], inv[4];
    #pragma unroll
    for (int r = 0; r < 4; ++r) {
        const int rl = wm * 16 + kg * 4 + r;
        float S = sred[0][rl] + sred[1][rl];
        float Q = qred[0][rl] + qred[1][rl];
        float mean = S * (1.0f / 256.0f);
        float var = Q * (1.0f / 256.0f) - mean * mean;
        mn[r] = mean; inv[r] = rsqrtf(var + 1e-5f);
    }
    #pragma unroll
    for (int n = 0; n < 8; ++n) {
        const int col = wn * 128 + n * 16 + r16;
        const float w = lnw[col], b = lnb[col];
        #pragma unroll
        for (int r = 0; r < 4; ++r) {
            const int row = row0 + wm * 16 + kg * 4 + r;
            float v = (acc[n][r] - mn[r]) * inv[r] * w + b;
            if (outf)  outf[(size_t)row * 256 + col] = v;
            if (outbf) outbf[(size_t)row * ldout + col] = f2bf(v);
        }
    }
}

// ---------------- fused gate GEMM + sigmoid + gated row-LayerNorm ----------------
// BM=16, BN=512 (full row in block), K=512. A = C2 [9600][512], Bt = gT [512][512].
// gates = sigmoid(A@B + gate_b) -> LDS (reuses Bs); t = g1*h1 + g2*ca; out = LN(t).
__global__ __launch_bounds__(256)
void gemm_gate_ln(const ushort_t* __restrict__ C2, const ushort_t* __restrict__ Bt,
                  const float* __restrict__ gb,
                  const float* __restrict__ lnw, const float* __restrict__ lnb,
                  float* __restrict__ outf, ushort_t* __restrict__ outbf)
{
    __shared__ ushort_t As[16 * 32];     // 1 KB
    __shared__ ushort_t Bs[512 * 32];    // 32 KB; reused as gates[16][512] bf16 after K-loop
    const int tid = threadIdx.x;
    const int row0 = blockIdx.x * 16;
    const int lane = tid & 63, wid = tid >> 6;
    const int r16 = lane & 15, kg = lane >> 4;
    const int rsub = lane >> 2, c8 = (lane & 3) * 8;

    f32x4 acc[8];
    #pragma unroll
    for (int n = 0; n < 8; ++n) { f32x4 z = {0.f,0.f,0.f,0.f}; acc[n] = z; }

    for (int k0 = 0; k0 < 512; k0 += 32) {
        if (wid == 0) {
            __builtin_amdgcn_global_load_lds(
                (const ga_u32*)(const void*)&C2[(size_t)(row0 + rsub) * 512 + k0 + c8],
                (ls_u32*)(void*)&As[0], 16, 0, 0);
        }
        #pragma unroll
        for (int i = wid; i < 32; i += 4) {
            const int r = i * 16 + rsub;
            __builtin_amdgcn_global_load_lds(
                (const ga_u32*)(const void*)&Bt[(size_t)r * 512 + k0 + c8],
                (ls_u32*)(void*)&Bs[i * 512], 16, 0, 0);
        }
        __syncthreads();
        short8 a = *(const short8*)&As[r16 * 32 + kg * 8];
        #pragma unroll
        for (int n = 0; n < 8; ++n) {
            short8 b = *(const short8*)&Bs[(wid * 128 + n * 16 + r16) * 32 + kg * 8];
            acc[n] = __builtin_amdgcn_mfma_f32_16x16x32_bf16(a, b, acc[n], 0, 0, 0);
        }
        __syncthreads();
    }

    // phase 1: sigmoid gates -> Bs as gates[16][512] bf16 (exactly 16 KB of the 32)
    ushort_t* gates = (ushort_t*)Bs;
    #pragma unroll
    for (int n = 0; n < 8; ++n) {
        const int col = wid * 128 + n * 16 + r16;
        const float gbv = gb[col];
        #pragma unroll
        for (int r = 0; r < 4; ++r) {
            const int row_l = kg * 4 + r;
            float g = 1.0f / (1.0f + __expf(-(acc[n][r] + gbv)));
            gates[row_l * 512 + col] = f2bf(g);
        }
    }
    __syncthreads();

    // phase 2: wave wid handles rows wid*4 .. +3; gated combine + row-LN over 256
    for (int j = 0; j < 4; ++j) {
        const int row_l = wid * 4 + j;
        const int row = row0 + row_l;
        us4 h14 = *(const us4*)&C2[(size_t)row * 512 + lane * 4];
        us4 ca4 = *(const us4*)&C2[(size_t)row * 512 + 256 + lane * 4];
        us4 g14 = *(const us4*)&gates[row_l * 512 + lane * 4];
        us4 g24 = *(const us4*)&gates[row_l * 512 + 256 + lane * 4];
        float v[4];
        float s = 0.f, s2 = 0.f;
        #pragma unroll
        for (int i = 0; i < 4; ++i) {
            v[i] = bf2f(g14[i]) * bf2f(h14[i]) + bf2f(g24[i]) * bf2f(ca4[i]);
            s += v[i]; s2 += v[i] * v[i];
        }
        #pragma unroll
        for (int off = 32; off; off >>= 1) {
            s += __shfl_xor(s, off); s2 += __shfl_xor(s2, off);
        }
        const float mean = s * (1.0f / 256.0f);
        const float var = s2 * (1.0f / 256.0f) - mean * mean;
        const float inv = rsqrtf(var + 1e-5f);
        f32x4 rf; us4 rb;
        #pragma unroll
        for (int i = 0; i < 4; ++i) {
            const int c = lane * 4 + i;
            float r = (v[i] - mean) * inv * lnw[c] + lnb[c];
            rf[i] = r; rb[i] = f2bf(r);
        }
        *(f32x4*)&outf[(size_t)row * 256 + lane * 4] = rf;
        *(us4*)&outbf[(size_t)row * 256 + lane * 4] = rb;
    }
}

// ---------------- MFMA flash attention (32-query chunks; QKV [9600][768]) ----------------
__global__ __launch_bounds__(256)
void attn_flash(const ushort_t* __restrict__ QKV, ushort_t* __restrict__ O)
{
    __shared__ ushort_t ks[64 * 40];
    __shared__ ushort_t vt[32 * 72];
    __shared__ float    ss[32 * 68];
    __shared__ ushort_t ps[32 * 72];
    __shared__ float    ml[32], ll[32], fl[32];

    const int orig = blockIdx.x;
    const int wg = (orig & 7) * 320 + (orig >> 3);   // 2560 = 8*320, bijective
    const int qc = wg % 10, bh = wg / 10;
    const int b = bh >> 3, h = bh & 7;
    const int q0 = qc * 32;
    const int nq = (BQ - q0 < 32) ? (BQ - q0) : 32;

    const int tid = threadIdx.x;
    const int lane = tid & 63, wid = tid >> 6;
    const int r16 = lane & 15, kg = lane >> 4;
    const int wm = wid >> 1, wn = wid & 1;

    if (tid < 32) { ml[tid] = -1e30f; ll[tid] = 0.f; }

    short8 aq[2];
    #pragma unroll
    for (int rt = 0; rt < 2; ++rt) {
        int qr = q0 + rt * 16 + r16;
        if (qr > BQ - 1) qr = BQ - 1;
        aq[rt] = *(const short8*)&QKV[((size_t)(b * BQ + qr)) * 768 + h * 32 + kg * 8];
    }
    f32x4 oacc = {0.f, 0.f, 0.f, 0.f};

    for (int kt = 0; kt < 5; ++kt) {
        __syncthreads();
        {
            int kk = tid >> 2, c8 = (tid & 3) * 8;
            int ki = kt * 64 + kk;
            short8 kv = {0, 0, 0, 0, 0, 0, 0, 0};
            short8 vv = {0, 0, 0, 0, 0, 0, 0, 0};
            if (ki < BQ) {
                size_t gi = ((size_t)(b * BQ + ki)) * 768 + h * 32 + c8;
                kv = *(const short8*)&QKV[gi + 256];
                vv = *(const short8*)&QKV[gi + 512];
            }
            *(short8*)&ks[kk * 40 + c8] = kv;
            #pragma unroll
            for (int j = 0; j < 8; ++j) vt[(c8 + j) * 72 + kk] = (ushort_t)vv[j];
        }
        __syncthreads();
        {
            short8 bk = *(const short8*)&ks[(wid * 16 + r16) * 40 + kg * 8];
            #pragma unroll
            for (int rt = 0; rt < 2; ++rt) {
                f32x4 sacc = {0.f, 0.f, 0.f, 0.f};
                sacc = __builtin_amdgcn_mfma_f32_16x16x32_bf16(aq[rt], bk, sacc, 0, 0, 0);
                #pragma unroll
                for (int r = 0; r < 4; ++r)
                    ss[(rt * 16 + kg * 4 + r) * 68 + wid * 16 + r16] = sacc[r];
            }
        }
        __syncthreads();
        #pragma unroll
        for (int j = 0; j < 8; ++j) {
            int row = wid * 8 + j;
            float s = ss[row * 68 + lane];
            if (kt * 64 + lane >= BQ) s = -1e30f;
            float tm = s;
            #pragma unroll
            for (int off = 32; off; off >>= 1) tm = fmaxf(tm, __shfl_xor(tm, off));
            float mold = ml[row];
            float mnew = fmaxf(mold, tm);
            float p = __expf(s - mnew);
            float psum = p;
            #pragma unroll
            for (int off = 32; off; off >>= 1) psum += __shfl_xor(psum, off);
            if (lane == 0) {
                float f = __expf(mold - mnew);
                ml[row] = mnew;
                ll[row] = ll[row] * f + psum;
                fl[row] = f;
            }
            ps[row * 72 + lane] = f2bf(p);
        }
        __syncthreads();
        {
            #pragma unroll
            for (int r = 0; r < 4; ++r)
                oacc[r] *= fl[wm * 16 + kg * 4 + r];
            #pragma unroll
            for (int kstep = 0; kstep < 2; ++kstep) {
                short8 pa = *(const short8*)&ps[(wm * 16 + r16) * 72 + kstep * 32 + kg * 8];
                short8 bv = *(const short8*)&vt[(wn * 16 + r16) * 72 + kstep * 32 + kg * 8];
                oacc = __builtin_amdgcn_mfma_f32_16x16x32_bf16(pa, bv, oacc, 0, 0, 0);
            }
        }
    }
    __syncthreads();
    #pragma unroll
    for (int r = 0; r < 4; ++r) {
        int rowl = wm * 16 + kg * 4 + r;
        if (rowl < nq) {
            float v = oacc[r] / ll[rowl];
            O[((size_t)(b * BQ + q0 + rowl)) * 256 + h * 32 + wn * 16 + r16] = f2bf(v);
        }
    }
}

// ---------------- deformable sampling (float4 gathers, 4 queries/block) ----------------
__global__ __launch_bounds__(256)
void sample_kernel(const float* __restrict__ enc, const float* __restrict__ offaw,
                   const float* __restrict__ ref, ushort_t* __restrict__ C2out)
{
    __shared__ float sofs[4][320];
    __shared__ float sref[4][4];

    const int orig = blockIdx.x;
    const int blk = (orig & 7) * 300 + (orig >> 3);   // 2400 = 8 * 300, bijective
    const int b = blk / 75;
    const int q0 = (blk % 75) * 4;
    const int tid = threadIdx.x;
    const int qq = tid >> 6;
    const int h = (tid >> 3) & 7;
    const int d4 = tid & 7;
    const int bq = b * BQ + q0 + qq;

    for (int e = tid; e < 4 * 80; e += 256) {
        int row = e / 80, c4 = e % 80;
        ((float4*)&sofs[row][0])[c4] =
            ((const float4*)(offaw + (size_t)(b * BQ + q0 + row) * 320))[c4];
    }
    if (tid < 16)
        sref[tid >> 2][tid & 3] = ref[(size_t)(b * BQ + q0 + (tid >> 2)) * 4 + (tid & 3)];
    __syncthreads();

    const float rx = sref[qq][0], ry = sref[qq][1];
    const float rw = sref[qq][2], rh = sref[qq][3];
    const float* op = &sofs[qq][h * 24];
    const float* ap = &sofs[qq][192 + h * 12];

    float wgt[12];
    float mx = -1e30f;
    #pragma unroll
    for (int j = 0; j < 12; ++j) { wgt[j] = ap[j]; mx = fmaxf(mx, wgt[j]); }
    float sum = 0.0f;
    #pragma unroll
    for (int j = 0; j < 12; ++j) { wgt[j] = __expf(wgt[j] - mx); sum += wgt[j]; }
    const float isum = 1.0f / sum;

    f32x4 acc = {0.f, 0.f, 0.f, 0.f};
    int p = 0;
    #pragma unroll
    for (int l = 0; l < 3; ++l) {
        const int Wl = (l == 0) ? 80 : (l == 1 ? 40 : 20);
        const int Hl = Wl;
        const int soff = (l == 0) ? 0 : (l == 1 ? 6400 : 8000);
        const float* base = enc + ((size_t)(b * SENC + soff)) * DIM + h * HD + d4 * 4;
        #pragma unroll
        for (int pp = 0; pp < 4; ++pp, ++p) {
            const float ox = op[p * 2 + 0], oy = op[p * 2 + 1];
            const float lx = rx + ox * 0.25f * rw * 0.5f;
            const float ly = ry + oy * 0.25f * rh * 0.5f;
            const float gx = lx * (float)Wl - 0.5f;
            const float gy = ly * (float)Hl - 0.5f;
            const float x0f = floorf(gx), y0f = floorf(gy);
            const int x0 = (int)x0f, y0 = (int)y0f;
            const float wx1 = gx - x0f, wy1 = gy - y0f;
            const float wx0 = 1.0f - wx1, wy0 = 1.0f - wy1;
            const bool vx0 = (x0 >= 0) & (x0 < Wl);
            const bool vx1 = (x0 + 1 >= 0) & (x0 + 1 < Wl);
            const bool vy0 = (y0 >= 0) & (y0 < Hl);
            const bool vy1 = (y0 + 1 >= 0) & (y0 + 1 < Hl);
            const int xc0 = min(max(x0, 0), Wl - 1);
            const int xc1 = min(max(x0 + 1, 0), Wl - 1);
            const int yc0 = min(max(y0, 0), Hl - 1);
            const int yc1 = min(max(y0 + 1, 0), Hl - 1);
            const float aw2 = wgt[p] * isum;
            const float w00 = wx0 * wy0 * ((vx0 & vy0) ? aw2 : 0.0f);
            const float w10 = wx1 * wy0 * ((vx1 & vy0) ? aw2 : 0.0f);
            const float w01 = wx0 * wy1 * ((vx0 & vy1) ? aw2 : 0.0f);
            const float w11 = wx1 * wy1 * ((vx1 & vy1) ? aw2 : 0.0f);
            f32x4 c00 = *(const f32x4*)&base[((size_t)(yc0 * Wl + xc0)) * DIM];
            f32x4 c10 = *(const f32x4*)&base[((size_t)(yc0 * Wl + xc1)) * DIM];
            f32x4 c01 = *(const f32x4*)&base[((size_t)(yc1 * Wl + xc0)) * DIM];
            f32x4 c11 = *(const f32x4*)&base[((size_t)(yc1 * Wl + xc1)) * DIM];
            #pragma unroll
            for (int r = 0; r < 4; ++r)
                acc[r] += w00 * c00[r] + w10 * c10[r] + w01 * c01[r] + w11 * c11[r];
        }
    }
    us4 u;
    u.x = f2bf(acc[0]); u.y = f2bf(acc[1]); u.z = f2bf(acc[2]); u.w = f2bf(acc[3]);
    *(us4*)&C2out[(size_t)bq * 512 + 256 + h * HD + d4 * 4] = u;
}

extern "C" void kernel_launch(void* const* d_in, const int* in_sizes, int n_in,
                              void* d_out, int out_size, void* d_ws, size_t ws_size,
                              hipStream_t stream)
{
    (void)in_sizes; (void)n_in; (void)out_size; (void)ws_size;
    const float* hidden   = (const float*)d_in[0];
    const float* pos      = (const float*)d_in[1];
    const float* ref      = (const float*)d_in[2];
    const float* enc      = (const float*)d_in[3];
    const float* q_w      = (const float*)d_in[4];
    const float* q_b      = (const float*)d_in[5];
    const float* k_w      = (const float*)d_in[6];
    const float* k_b      = (const float*)d_in[7];
    const float* v_w      = (const float*)d_in[8];
    const float* v_b      = (const float*)d_in[9];
    const float* o_w      = (const float*)d_in[10];
    const float* o_b      = (const float*)d_in[11];
    const float* sa_ln_w  = (const float*)d_in[12];
    const float* sa_ln_b  = (const float*)d_in[13];
    const float* off_w    = (const float*)d_in[14];
    const float* off_b    = (const float*)d_in[15];
    const float* aw_w     = (const float*)d_in[16];
    const float* aw_b     = (const float*)d_in[17];
    const float* gate_w   = (const float*)d_in[18];
    const float* gate_b   = (const float*)d_in[19];
    const float* gate_ln_w= (const float*)d_in[20];
    const float* gate_ln_b= (const float*)d_in[21];
    const float* fc1_w    = (const float*)d_in[22];
    const float* fc1_b    = (const float*)d_in[23];
    const float* fc2_w    = (const float*)d_in[24];
    const float* fc2_b    = (const float*)d_in[25];
    const float* fin_ln_w = (const float*)d_in[26];
    const float* fin_ln_b = (const float*)d_in[27];
    float* out = (float*)d_out;

    char* wsb = (char*)d_ws;
    ushort_t* hqbf   = (ushort_t*)(wsb + 0);          // [9600][256] bf16
    ushort_t* hidbf  = (ushort_t*)(wsb + 4915200);    // [9600][256] bf16
    ushort_t* QKV    = (ushort_t*)(wsb + 9830400);    // [9600][768] bf16 (ends 24576000)
    ushort_t* aobf   = (ushort_t*)(wsb + 24576000);   // [9600][256] bf16
    ushort_t* C2     = (ushort_t*)(wsb + 9830400);    // [9600][512] bf16 (reuse q|k)
    float*    offaw  = (float*)(wsb + 19660800);      // [9600][320] f32 (reuse v/ao)
    ushort_t* midbf  = (ushort_t*)(wsb + 19660800);   // [9600][1024] bf16 (reuse offaw)
    ushort_t* h2bf   = (ushort_t*)(wsb + 39321600);   // [9600][256] bf16
    ushort_t* qkvT   = (ushort_t*)(wsb + 44236800);   // 768x256 (q|k|v)
    ushort_t* oT     = (ushort_t*)(wsb + 44630016);   // 256x256
    ushort_t* offawT = (ushort_t*)(wsb + 44761088);   // 320x256
    ushort_t* gT     = (ushort_t*)(wsb + 44924928);   // 512x512
    ushort_t* f1T    = (ushort_t*)(wsb + 45449216);   // 1024x256
    ushort_t* f2T    = (ushort_t*)(wsb + 45973504);   // 256x1024
    float*    qkvb   = (float*)(wsb + 46497792);      // 768 f32

    const dim3 blk(256);
    const float scal = 0.17677669529663687f;  // 32^-0.5
    const int BIG = 1 << 30;

    prep_all<<<dim3(3505), blk, 0, stream>>>(hidden, pos, hqbf, hidbf,
                                             q_w, k_w, v_w, o_w, off_w, aw_w,
                                             gate_w, fc1_w, fc2_w,
                                             qkvT, oT, offawT, gT, f1T, f2T,
                                             q_b, k_b, v_b, qkvb, scal);

    // fused q|k|v projection: cols<512 use hq, cols>=512 use hid
    gemm_mfma<64,128,0,true><<<dim3(6,150), blk, 0, stream>>>(hqbf, hidbf, 512, 256, qkvT, 256, qkvb, nullptr, 768, 768, nullptr, QKV, 768);

    // self-attention
    attn_flash<<<dim3(2560), blk, 0, stream>>>(QKV, aobf);

    // fused o-projection + LN(hidden + sa) -> C2[:, :256] bf16
    gemm_ln<<<dim3(300), blk, 0, stream>>>(aobf, 256, oT, 256, o_b, hidden,
                                           sa_ln_w, sa_ln_b, nullptr, C2, 512);

    // offsets|aw combined (N=288, pad 320)
    gemm_mfma<64,64,0,false><<<dim3(5,150), blk, 0, stream>>>(C2, nullptr, BIG, 512, offawT, 256, off_b, aw_b, 192, 288, offaw, nullptr, 320);

    // deformable sampling (softmax fused) -> C2[:, 256:]
    sample_kernel<<<dim3(2400), blk, 0, stream>>>(enc, offaw, ref, C2);

    // fused gate GEMM + sigmoid + gated LN -> out (H2 f32) + h2bf
    gemm_gate_ln<<<dim3(600), blk, 0, stream>>>(C2, gT, gate_b, gate_ln_w, gate_ln_b, out, h2bf);

    // FFN: fc1 -> midbf ; fused fc2 + LN(H2 + ffn) -> out
    gemm_mfma<128,128,1,true><<<dim3(8,75), blk, 0, stream>>>(h2bf, nullptr, BIG, 256, f1T, 256, fc1_b, nullptr, 1024, 1024, nullptr, midbf, 1024);
    gemm_ln<<<dim3(300), blk, 0, stream>>>(midbf, 1024, f2T, 1024, fc2_b, out,
                                           fin_ln_w, fin_ln_b, out, nullptr, 0);
}

// Round 11
// 238.235 us; speedup vs baseline: 1.0353x; 1.0353x over previous
//
#include <hip/hip_runtime.h>
#include <cmath>

#define BQ 300
#define DIM 256
#define NH 8
#define HD 32
#define NB 32
#define MROWS 9600
#define SENC 8400

typedef unsigned short ushort_t;
typedef __attribute__((ext_vector_type(8))) short short8;
typedef __attribute__((ext_vector_type(4))) float f32x4;
typedef __attribute__((ext_vector_type(4))) unsigned short us4;
typedef __attribute__((address_space(1))) unsigned int ga_u32;
typedef __attribute__((address_space(3))) unsigned int ls_u32;

__device__ __forceinline__ float bf2f(ushort_t u) {
    union { unsigned u32; float f; } x; x.u32 = ((unsigned)u) << 16; return x.f;
}
__device__ __forceinline__ ushort_t f2bf(float f) {
    union { float f; unsigned u; } x; x.f = f;
    unsigned u = x.u;
    u += 0x7fffu + ((u >> 16) & 1u);
    return (ushort_t)(u >> 16);
}

// ---------------- prep: activation cvt (single pass) + weight transposes ----------------
__global__ __launch_bounds__(256)
void prep_all(const float* __restrict__ hidden, const float* __restrict__ pos,
              ushort_t* __restrict__ hq, ushort_t* __restrict__ hid,
              const float* __restrict__ q_w, const float* __restrict__ k_w,
              const float* __restrict__ v_w, const float* __restrict__ o_w,
              const float* __restrict__ off_w, const float* __restrict__ aw_w,
              const float* __restrict__ gate_w, const float* __restrict__ fc1_w,
              const float* __restrict__ fc2_w,
              ushort_t* __restrict__ qkvT, ushort_t* __restrict__ oT,
              ushort_t* __restrict__ offawT, ushort_t* __restrict__ gT,
              ushort_t* __restrict__ f1T, ushort_t* __restrict__ f2T,
              const float* __restrict__ q_b, const float* __restrict__ k_b,
              const float* __restrict__ v_b, float* __restrict__ qkvb,
              float scal)
{
    const int tid = threadIdx.x;
    if (blockIdx.x < 2400) {
        int i = blockIdx.x * 256 + tid;   // 0 .. 614399 float4s
        float4 a = ((const float4*)hidden)[i];
        float4 b = ((const float4*)pos)[i];
        us4 uq, uh;
        uq.x = f2bf(a.x + b.x); uq.y = f2bf(a.y + b.y);
        uq.z = f2bf(a.z + b.z); uq.w = f2bf(a.w + b.w);
        uh.x = f2bf(a.x); uh.y = f2bf(a.y); uh.z = f2bf(a.z); uh.w = f2bf(a.w);
        *(us4*)&hq[(size_t)i * 4] = uq;
        *(us4*)&hid[(size_t)i * 4] = uh;
        return;
    }
    __shared__ float t[32][33];
    const int bid = blockIdx.x - 2400;
    const float* src; ushort_t* dst; int K, N, local; float scale = 1.0f;

    if (bid < 64)       { src = q_w;   dst = qkvT;             K = 256; N = 256;  local = bid;       scale = scal; }
    else if (bid < 128) { src = k_w;   dst = qkvT + 256 * 256; K = 256; N = 256;  local = bid - 64; }
    else if (bid < 192) { src = v_w;   dst = qkvT + 512 * 256; K = 256; N = 256;  local = bid - 128; }
    else if (bid < 256) { src = o_w;   dst = oT;               K = 256; N = 256;  local = bid - 192; }
    else if (bid < 304) { src = off_w; dst = offawT;           K = 256; N = 192;  local = bid - 256; }
    else if (bid < 328) { src = aw_w;  dst = offawT + 192 * 256; K = 256; N = 96; local = bid - 304; }
    else if (bid < 336) {   // zero-fill offawT rows 288..319
        int l = bid - 328;
        ushort_t* d2 = offawT + 288 * 256 + l * 32;
        for (int e = tid; e < 32 * 32; e += 256) { int r = e >> 5, c = e & 31; d2[r * 256 + c] = 0; }
        return;
    }
    else if (bid < 592) { src = gate_w; dst = gT;  K = 512;  N = 512;  local = bid - 336; }
    else if (bid < 848) { src = fc1_w;  dst = f1T; K = 256;  N = 1024; local = bid - 592; }
    else if (bid < 1104){ src = fc2_w;  dst = f2T; K = 1024; N = 256;  local = bid - 848; }
    else {  // combined qkv bias (q scaled)
        #pragma unroll
        for (int j = 0; j < 3; ++j) {
            int c = j * 256 + tid;
            float v = (j == 0) ? q_b[tid] * scal : (j == 1) ? k_b[tid] : v_b[tid];
            qkvb[c] = v;
        }
        return;
    }
    const int tilesx = N >> 5;
    const int n0 = (local % tilesx) * 32, k0 = (local / tilesx) * 32;
    const int tx = tid & 31, ty = tid >> 5;
    #pragma unroll
    for (int i = 0; i < 4; ++i)
        t[ty + i * 8][tx] = src[(size_t)(k0 + ty + i * 8) * N + n0 + tx];
    __syncthreads();
    #pragma unroll
    for (int i = 0; i < 4; ++i)
        dst[(size_t)(n0 + ty + i * 8) * K + k0 + tx] = f2bf(t[tx][ty + i * 8] * scale);
}

// ---------------- MFMA GEMM (global_load_lds staging, linear LDS) ----------------
template<int BM, int BN, int ACT, bool OBF>
__global__ __launch_bounds__(256)
void gemm_mfma(const ushort_t* __restrict__ A1, const ushort_t* __restrict__ A2,
               int asplit, int lda,
               const ushort_t* __restrict__ Bt, int K,
               const float* __restrict__ bias, const float* __restrict__ bias2,
               int bsplit, int N,
               float* __restrict__ Cf, ushort_t* __restrict__ Cb, int ldc)
{
    __shared__ ushort_t As[BM * 32];
    __shared__ ushort_t Bs[BN * 32];
    const int tid = threadIdx.x;
    const int row0 = blockIdx.y * BM, col0 = blockIdx.x * BN;
    const ushort_t* __restrict__ A = (col0 < asplit) ? A1 : A2;
    const int lane = tid & 63, wid = tid >> 6;
    const int wm = wid >> 1, wn = wid & 1;
    constexpr int FM = BM / 32, FN = BN / 32;
    const int r16 = lane & 15, kg = lane >> 4;
    const int rsub = lane >> 2, c8 = (lane & 3) * 8;   // staging lane map: 4 lanes/row

    f32x4 acc[FM][FN];
    #pragma unroll
    for (int m = 0; m < FM; ++m)
        #pragma unroll
        for (int n = 0; n < FN; ++n) {
            f32x4 z = {0.f, 0.f, 0.f, 0.f};
            acc[m][n] = z;
        }

    for (int k0 = 0; k0 < K; k0 += 32) {
        #pragma unroll
        for (int i = wid; i < BM / 16; i += 4) {
            const int r = i * 16 + rsub;
            __builtin_amdgcn_global_load_lds(
                (const ga_u32*)(const void*)&A[(size_t)(row0 + r) * lda + k0 + c8],
                (ls_u32*)(void*)&As[i * 512], 16, 0, 0);
        }
        #pragma unroll
        for (int i = wid; i < BN / 16; i += 4) {
            const int r = i * 16 + rsub;
            __builtin_amdgcn_global_load_lds(
                (const ga_u32*)(const void*)&Bt[(size_t)(col0 + r) * K + k0 + c8],
                (ls_u32*)(void*)&Bs[i * 512], 16, 0, 0);
        }
        __syncthreads();
        short8 a[FM], b[FN];
        #pragma unroll
        for (int m = 0; m < FM; ++m)
            a[m] = *(const short8*)&As[(wm * (BM / 2) + m * 16 + r16) * 32 + kg * 8];
        #pragma unroll
        for (int n = 0; n < FN; ++n)
            b[n] = *(const short8*)&Bs[(wn * (BN / 2) + n * 16 + r16) * 32 + kg * 8];
        #pragma unroll
        for (int m = 0; m < FM; ++m)
            #pragma unroll
            for (int n = 0; n < FN; ++n)
                acc[m][n] = __builtin_amdgcn_mfma_f32_16x16x32_bf16(a[m], b[n], acc[m][n], 0, 0, 0);
        __syncthreads();
    }

    #pragma unroll
    for (int m = 0; m < FM; ++m) {
        #pragma unroll
        for (int n = 0; n < FN; ++n) {
            int colb = col0 + wn * (BN / 2) + n * 16 + r16;
            float bs;
            if (colb < bsplit) bs = bias[colb];
            else if (colb < N) bs = bias2[colb - bsplit];
            else bs = 0.0f;
            #pragma unroll
            for (int r = 0; r < 4; ++r) {
                int row = row0 + wm * (BM / 2) + m * 16 + kg * 4 + r;
                float v = acc[m][n][r] + bs;
                if (ACT == 1) v = fmaxf(v, 0.0f);
                if (ACT == 2) v = 1.0f / (1.0f + __expf(-v));
                if (OBF) Cb[(size_t)row * ldc + colb] = f2bf(v);
                else     Cf[(size_t)row * ldc + colb] = v;
            }
        }
    }
}

// ---------------- fused GEMM + row-LayerNorm ----------------
__global__ __launch_bounds__(256)
void gemm_ln(const ushort_t* __restrict__ A, int lda,
             const ushort_t* __restrict__ Bt, int K,
             const float* __restrict__ gb, const float* __restrict__ Y,
             const float* __restrict__ lnw, const float* __restrict__ lnb,
             float* __restrict__ outf, ushort_t* __restrict__ outbf, int ldout)
{
    constexpr int LDT = 40;
    __shared__ ushort_t As[32 * LDT];
    __shared__ ushort_t Bs[256 * LDT];
    __shared__ float sred[2][32], qred[2][32];
    const int tid = threadIdx.x;
    const int row0 = blockIdx.x * 32;
    const int lane = tid & 63, wid = tid >> 6;
    const int wm = wid >> 1, wn = wid & 1;
    const int r16 = lane & 15, kg = lane >> 4;

    f32x4 acc[8];
    #pragma unroll
    for (int n = 0; n < 8; ++n) { f32x4 z = {0.f,0.f,0.f,0.f}; acc[n] = z; }

    for (int k0 = 0; k0 < K; k0 += 32) {
        if (tid < 128) {
            int r = tid >> 2, cc = tid & 3;
            *(short8*)&As[r * LDT + cc * 8] =
                *(const short8*)&A[(size_t)(row0 + r) * lda + k0 + cc * 8];
        }
        #pragma unroll
        for (int c = 0; c < 4; ++c) {
            int idx = tid + c * 256;
            int r = idx >> 2, cc = idx & 3;
            *(short8*)&Bs[r * LDT + cc * 8] =
                *(const short8*)&Bt[(size_t)r * K + k0 + cc * 8];
        }
        __syncthreads();
        short8 a = *(const short8*)&As[(wm * 16 + r16) * LDT + kg * 8];
        #pragma unroll
        for (int n = 0; n < 8; ++n) {
            short8 b = *(const short8*)&Bs[(wn * 128 + n * 16 + r16) * LDT + kg * 8];
            acc[n] = __builtin_amdgcn_mfma_f32_16x16x32_bf16(a, b, acc[n], 0, 0, 0);
        }
        __syncthreads();
    }

    float s[4] = {0.f, 0.f, 0.f, 0.f}, q[4] = {0.f, 0.f, 0.f, 0.f};
    #pragma unroll
    for (int n = 0; n < 8; ++n) {
        const int col = wn * 128 + n * 16 + r16;
        const float gbv = gb[col];
        #pragma unroll
        for (int r = 0; r < 4; ++r) {
            const int row = row0 + wm * 16 + kg * 4 + r;
            float t = acc[n][r] + gbv + Y[(size_t)row * 256 + col];
            acc[n][r] = t;
            s[r] += t; q[r] += t * t;
        }
    }
    #pragma unroll
    for (int off = 1; off < 16; off <<= 1) {
        #pragma unroll
        for (int r = 0; r < 4; ++r) {
            s[r] += __shfl_xor(s[r], off);
            q[r] += __shfl_xor(q[r], off);
        }
    }
    if (r16 == 0) {
        #pragma unroll
        for (int r = 0; r < 4; ++r) {
            sred[wn][wm * 16 + kg * 4 + r] = s[r];
            qred[wn][wm * 16 + kg * 4 + r] = q[r];
        }
    }
    __syncthreads();
    float mn[4], inv[4];
    #pragma unroll
    for (int r = 0; r < 4; ++r) {
        const int rl = wm * 16 + kg * 4 + r;
        float S = sred[0][rl] + sred[1][rl];
        float Q = qred[0][rl] + qred[1][rl];
        float mean = S * (1.0f / 256.0f);
        float var = Q * (1.0f / 256.0f) - mean * mean;
        mn[r] = mean; inv[r] = rsqrtf(var + 1e-5f);
    }
    #pragma unroll
    for (int n = 0; n < 8; ++n) {
        const int col = wn * 128 + n * 16 + r16;
        const float w = lnw[col], b = lnb[col];
        #pragma unroll
        for (int r = 0; r < 4; ++r) {
            const int row = row0 + wm * 16 + kg * 4 + r;
            float v = (acc[n][r] - mn[r]) * inv[r] * w + b;
            if (outf)  outf[(size_t)row * 256 + col] = v;
            if (outbf) outbf[(size_t)row * ldout + col] = f2bf(v);
        }
    }
}

// ---------------- MFMA flash attention (32-query chunks; QKV [9600][768]) ----------------
__global__ __launch_bounds__(256)
void attn_flash(const ushort_t* __restrict__ QKV, ushort_t* __restrict__ O)
{
    __shared__ ushort_t ks[64 * 40];
    __shared__ ushort_t vt[32 * 72];
    __shared__ float    ss[32 * 68];
    __shared__ ushort_t ps[32 * 72];
    __shared__ float    ml[32], ll[32], fl[32];

    const int orig = blockIdx.x;
    const int wg = (orig & 7) * 320 + (orig >> 3);   // 2560 = 8*320, bijective
    const int qc = wg % 10, bh = wg / 10;
    const int b = bh >> 3, h = bh & 7;
    const int q0 = qc * 32;
    const int nq = (BQ - q0 < 32) ? (BQ - q0) : 32;

    const int tid = threadIdx.x;
    const int lane = tid & 63, wid = tid >> 6;
    const int r16 = lane & 15, kg = lane >> 4;
    const int wm = wid >> 1, wn = wid & 1;

    if (tid < 32) { ml[tid] = -1e30f; ll[tid] = 0.f; }

    short8 aq[2];
    #pragma unroll
    for (int rt = 0; rt < 2; ++rt) {
        int qr = q0 + rt * 16 + r16;
        if (qr > BQ - 1) qr = BQ - 1;
        aq[rt] = *(const short8*)&QKV[((size_t)(b * BQ + qr)) * 768 + h * 32 + kg * 8];
    }
    f32x4 oacc = {0.f, 0.f, 0.f, 0.f};

    for (int kt = 0; kt < 5; ++kt) {
        __syncthreads();
        {
            int kk = tid >> 2, c8 = (tid & 3) * 8;
            int ki = kt * 64 + kk;
            short8 kv = {0, 0, 0, 0, 0, 0, 0, 0};
            short8 vv = {0, 0, 0, 0, 0, 0, 0, 0};
            if (ki < BQ) {
                size_t gi = ((size_t)(b * BQ + ki)) * 768 + h * 32 + c8;
                kv = *(const short8*)&QKV[gi + 256];
                vv = *(const short8*)&QKV[gi + 512];
            }
            *(short8*)&ks[kk * 40 + c8] = kv;
            #pragma unroll
            for (int j = 0; j < 8; ++j) vt[(c8 + j) * 72 + kk] = (ushort_t)vv[j];
        }
        __syncthreads();
        {
            short8 bk = *(const short8*)&ks[(wid * 16 + r16) * 40 + kg * 8];
            #pragma unroll
            for (int rt = 0; rt < 2; ++rt) {
                f32x4 sacc = {0.f, 0.f, 0.f, 0.f};
                sacc = __builtin_amdgcn_mfma_f32_16x16x32_bf16(aq[rt], bk, sacc, 0, 0, 0);
                #pragma unroll
                for (int r = 0; r < 4; ++r)
                    ss[(rt * 16 + kg * 4 + r) * 68 + wid * 16 + r16] = sacc[r];
            }
        }
        __syncthreads();
        #pragma unroll
        for (int j = 0; j < 8; ++j) {
            int row = wid * 8 + j;
            float s = ss[row * 68 + lane];
            if (kt * 64 + lane >= BQ) s = -1e30f;
            float tm = s;
            #pragma unroll
            for (int off = 32; off; off >>= 1) tm = fmaxf(tm, __shfl_xor(tm, off));
            float mold = ml[row];
            float mnew = fmaxf(mold, tm);
            float p = __expf(s - mnew);
            float psum = p;
            #pragma unroll
            for (int off = 32; off; off >>= 1) psum += __shfl_xor(psum, off);
            if (lane == 0) {
                float f = __expf(mold - mnew);
                ml[row] = mnew;
                ll[row] = ll[row] * f + psum;
                fl[row] = f;
            }
            ps[row * 72 + lane] = f2bf(p);
        }
        __syncthreads();
        {
            #pragma unroll
            for (int r = 0; r < 4; ++r)
                oacc[r] *= fl[wm * 16 + kg * 4 + r];
            #pragma unroll
            for (int kstep = 0; kstep < 2; ++kstep) {
                short8 pa = *(const short8*)&ps[(wm * 16 + r16) * 72 + kstep * 32 + kg * 8];
                short8 bv = *(const short8*)&vt[(wn * 16 + r16) * 72 + kstep * 32 + kg * 8];
                oacc = __builtin_amdgcn_mfma_f32_16x16x32_bf16(pa, bv, oacc, 0, 0, 0);
            }
        }
    }
    __syncthreads();
    #pragma unroll
    for (int r = 0; r < 4; ++r) {
        int rowl = wm * 16 + kg * 4 + r;
        if (rowl < nq) {
            float v = oacc[r] / ll[rowl];
            O[((size_t)(b * BQ + q0 + rowl)) * 256 + h * 32 + wn * 16 + r16] = f2bf(v);
        }
    }
}

// ---------------- gated LayerNorm ----------------
__global__ __launch_bounds__(256)
void ln_gate(const ushort_t* __restrict__ C2, const ushort_t* __restrict__ G,
             const float* __restrict__ w, const float* __restrict__ b,
             float* __restrict__ outf, ushort_t* __restrict__ outbf)
{
    const int row = blockIdx.x * 4 + (threadIdx.x >> 6);
    const int lane = threadIdx.x & 63;
    float v[4];
    #pragma unroll
    for (int i = 0; i < 4; ++i) {
        int c = lane + 64 * i;
        float h1 = bf2f(C2[(size_t)row * 512 + c]);
        float ca = bf2f(C2[(size_t)row * 512 + 256 + c]);
        float g1 = bf2f(G[(size_t)row * 512 + c]);
        float g2 = bf2f(G[(size_t)row * 512 + 256 + c]);
        v[i] = g1 * h1 + g2 * ca;
    }
    float s = v[0] + v[1] + v[2] + v[3];
    float s2 = v[0]*v[0] + v[1]*v[1] + v[2]*v[2] + v[3]*v[3];
    #pragma unroll
    for (int off = 32; off; off >>= 1) { s += __shfl_xor(s, off); s2 += __shfl_xor(s2, off); }
    const float mean = s * (1.0f / DIM);
    const float var = s2 * (1.0f / DIM) - mean * mean;
    const float inv = rsqrtf(var + 1e-5f);
    #pragma unroll
    for (int i = 0; i < 4; ++i) {
        int c = lane + 64 * i;
        float r = (v[i] - mean) * inv * w[c] + b[c];
        outf[(size_t)row * DIM + c] = r;
        outbf[(size_t)row * DIM + c] = f2bf(r);
    }
}

// ---------------- deformable sampling (float4 gathers, 4 queries/block) ----------------
__global__ __launch_bounds__(256)
void sample_kernel(const float* __restrict__ enc, const float* __restrict__ offaw,
                   const float* __restrict__ ref, ushort_t* __restrict__ C2out)
{
    __shared__ float sofs[4][320];
    __shared__ float sref[4][4];

    const int orig = blockIdx.x;
    const int blk = (orig & 7) * 300 + (orig >> 3);   // 2400 = 8 * 300, bijective
    const int b = blk / 75;
    const int q0 = (blk % 75) * 4;
    const int tid = threadIdx.x;
    const int qq = tid >> 6;
    const int h = (tid >> 3) & 7;
    const int d4 = tid & 7;
    const int bq = b * BQ + q0 + qq;

    for (int e = tid; e < 4 * 80; e += 256) {
        int row = e / 80, c4 = e % 80;
        ((float4*)&sofs[row][0])[c4] =
            ((const float4*)(offaw + (size_t)(b * BQ + q0 + row) * 320))[c4];
    }
    if (tid < 16)
        sref[tid >> 2][tid & 3] = ref[(size_t)(b * BQ + q0 + (tid >> 2)) * 4 + (tid & 3)];
    __syncthreads();

    const float rx = sref[qq][0], ry = sref[qq][1];
    const float rw = sref[qq][2], rh = sref[qq][3];
    const float* op = &sofs[qq][h * 24];
    const float* ap = &sofs[qq][192 + h * 12];

    float wgt[12];
    float mx = -1e30f;
    #pragma unroll
    for (int j = 0; j < 12; ++j) { wgt[j] = ap[j]; mx = fmaxf(mx, wgt[j]); }
    float sum = 0.0f;
    #pragma unroll
    for (int j = 0; j < 12; ++j) { wgt[j] = __expf(wgt[j] - mx); sum += wgt[j]; }
    const float isum = 1.0f / sum;

    f32x4 acc = {0.f, 0.f, 0.f, 0.f};
    int p = 0;
    #pragma unroll
    for (int l = 0; l < 3; ++l) {
        const int Wl = (l == 0) ? 80 : (l == 1 ? 40 : 20);
        const int Hl = Wl;
        const int soff = (l == 0) ? 0 : (l == 1 ? 6400 : 8000);
        const float* base = enc + ((size_t)(b * SENC + soff)) * DIM + h * HD + d4 * 4;
        #pragma unroll
        for (int pp = 0; pp < 4; ++pp, ++p) {
            const float ox = op[p * 2 + 0], oy = op[p * 2 + 1];
            const float lx = rx + ox * 0.25f * rw * 0.5f;
            const float ly = ry + oy * 0.25f * rh * 0.5f;
            const float gx = lx * (float)Wl - 0.5f;
            const float gy = ly * (float)Hl - 0.5f;
            const float x0f = floorf(gx), y0f = floorf(gy);
            const int x0 = (int)x0f, y0 = (int)y0f;
            const float wx1 = gx - x0f, wy1 = gy - y0f;
            const float wx0 = 1.0f - wx1, wy0 = 1.0f - wy1;
            const bool vx0 = (x0 >= 0) & (x0 < Wl);
            const bool vx1 = (x0 + 1 >= 0) & (x0 + 1 < Wl);
            const bool vy0 = (y0 >= 0) & (y0 < Hl);
            const bool vy1 = (y0 + 1 >= 0) & (y0 + 1 < Hl);
            const int xc0 = min(max(x0, 0), Wl - 1);
            const int xc1 = min(max(x0 + 1, 0), Wl - 1);
            const int yc0 = min(max(y0, 0), Hl - 1);
            const int yc1 = min(max(y0 + 1, 0), Hl - 1);
            const float aw2 = wgt[p] * isum;
            const float w00 = wx0 * wy0 * ((vx0 & vy0) ? aw2 : 0.0f);
            const float w10 = wx1 * wy0 * ((vx1 & vy0) ? aw2 : 0.0f);
            const float w01 = wx0 * wy1 * ((vx0 & vy1) ? aw2 : 0.0f);
            const float w11 = wx1 * wy1 * ((vx1 & vy1) ? aw2 : 0.0f);
            f32x4 c00 = *(const f32x4*)&base[((size_t)(yc0 * Wl + xc0)) * DIM];
            f32x4 c10 = *(const f32x4*)&base[((size_t)(yc0 * Wl + xc1)) * DIM];
            f32x4 c01 = *(const f32x4*)&base[((size_t)(yc1 * Wl + xc0)) * DIM];
            f32x4 c11 = *(const f32x4*)&base[((size_t)(yc1 * Wl + xc1)) * DIM];
            #pragma unroll
            for (int r = 0; r < 4; ++r)
                acc[r] += w00 * c00[r] + w10 * c10[r] + w01 * c01[r] + w11 * c11[r];
        }
    }
    us4 u;
    u.x = f2bf(acc[0]); u.y = f2bf(acc[1]); u.z = f2bf(acc[2]); u.w = f2bf(acc[3]);
    *(us4*)&C2out[(size_t)bq * 512 + 256 + h * HD + d4 * 4] = u;
}

extern "C" void kernel_launch(void* const* d_in, const int* in_sizes, int n_in,
                              void* d_out, int out_size, void* d_ws, size_t ws_size,
                              hipStream_t stream)
{
    (void)in_sizes; (void)n_in; (void)out_size; (void)ws_size;
    const float* hidden   = (const float*)d_in[0];
    const float* pos      = (const float*)d_in[1];
    const float* ref      = (const float*)d_in[2];
    const float* enc      = (const float*)d_in[3];
    const float* q_w      = (const float*)d_in[4];
    const float* q_b      = (const float*)d_in[5];
    const float* k_w      = (const float*)d_in[6];
    const float* k_b      = (const float*)d_in[7];
    const float* v_w      = (const float*)d_in[8];
    const float* v_b      = (const float*)d_in[9];
    const float* o_w      = (const float*)d_in[10];
    const float* o_b      = (const float*)d_in[11];
    const float* sa_ln_w  = (const float*)d_in[12];
    const float* sa_ln_b  = (const float*)d_in[13];
    const float* off_w    = (const float*)d_in[14];
    const float* off_b    = (const float*)d_in[15];
    const float* aw_w     = (const float*)d_in[16];
    const float* aw_b     = (const float*)d_in[17];
    const float* gate_w   = (const float*)d_in[18];
    const float* gate_b   = (const float*)d_in[19];
    const float* gate_ln_w= (const float*)d_in[20];
    const float* gate_ln_b= (const float*)d_in[21];
    const float* fc1_w    = (const float*)d_in[22];
    const float* fc1_b    = (const float*)d_in[23];
    const float* fc2_w    = (const float*)d_in[24];
    const float* fc2_b    = (const float*)d_in[25];
    const float* fin_ln_w = (const float*)d_in[26];
    const float* fin_ln_b = (const float*)d_in[27];
    float* out = (float*)d_out;

    char* wsb = (char*)d_ws;
    ushort_t* hqbf   = (ushort_t*)(wsb + 0);          // [9600][256] bf16
    ushort_t* hidbf  = (ushort_t*)(wsb + 4915200);    // [9600][256] bf16
    ushort_t* QKV    = (ushort_t*)(wsb + 9830400);    // [9600][768] bf16 (ends 24576000)
    ushort_t* aobf   = (ushort_t*)(wsb + 24576000);   // [9600][256] bf16
    ushort_t* C2     = (ushort_t*)(wsb + 9830400);    // [9600][512] bf16 (reuse q|k)
    float*    offaw  = (float*)(wsb + 19660800);      // [9600][320] f32 (reuse v/ao)
    ushort_t* gatesbf= (ushort_t*)(wsb + 0);          // [9600][512] bf16 (reuse hq/hid)
    ushort_t* midbf  = (ushort_t*)(wsb + 19660800);   // [9600][1024] bf16 (reuse offaw)
    ushort_t* h2bf   = (ushort_t*)(wsb + 39321600);   // [9600][256] bf16
    ushort_t* qkvT   = (ushort_t*)(wsb + 44236800);   // 768x256 (q|k|v)
    ushort_t* oT     = (ushort_t*)(wsb + 44630016);   // 256x256
    ushort_t* offawT = (ushort_t*)(wsb + 44761088);   // 320x256
    ushort_t* gT     = (ushort_t*)(wsb + 44924928);   // 512x512
    ushort_t* f1T    = (ushort_t*)(wsb + 45449216);   // 1024x256
    ushort_t* f2T    = (ushort_t*)(wsb + 45973504);   // 256x1024
    float*    qkvb   = (float*)(wsb + 46497792);      // 768 f32

    const dim3 blk(256);
    const float scal = 0.17677669529663687f;  // 32^-0.5
    const int BIG = 1 << 30;

    prep_all<<<dim3(3505), blk, 0, stream>>>(hidden, pos, hqbf, hidbf,
                                             q_w, k_w, v_w, o_w, off_w, aw_w,
                                             gate_w, fc1_w, fc2_w,
                                             qkvT, oT, offawT, gT, f1T, f2T,
                                             q_b, k_b, v_b, qkvb, scal);

    // fused q|k|v projection: cols<512 use hq, cols>=512 use hid
    gemm_mfma<64,128,0,true><<<dim3(6,150), blk, 0, stream>>>(hqbf, hidbf, 512, 256, qkvT, 256, qkvb, nullptr, 768, 768, nullptr, QKV, 768);

    // self-attention
    attn_flash<<<dim3(2560), blk, 0, stream>>>(QKV, aobf);

    // fused o-projection + LN(hidden + sa) -> C2[:, :256] bf16
    gemm_ln<<<dim3(300), blk, 0, stream>>>(aobf, 256, oT, 256, o_b, hidden,
                                           sa_ln_w, sa_ln_b, nullptr, C2, 512);

    // offsets|aw combined (N=288, pad 320)
    gemm_mfma<64,64,0,false><<<dim3(5,150), blk, 0, stream>>>(C2, nullptr, BIG, 512, offawT, 256, off_b, aw_b, 192, 288, offaw, nullptr, 320);

    // deformable sampling (softmax fused) -> C2[:, 256:]
    sample_kernel<<<dim3(2400), blk, 0, stream>>>(enc, offaw, ref, C2);

    // gates (sigmoid) ; gated LN -> out (H2) + h2bf
    gemm_mfma<64,128,2,true><<<dim3(4,150), blk, 0, stream>>>(C2, nullptr, BIG, 512, gT, 512, gate_b, nullptr, 512, 512, nullptr, gatesbf, 512);
    ln_gate<<<dim3(2400), blk, 0, stream>>>(C2, gatesbf, gate_ln_w, gate_ln_b, out, h2bf);

    // FFN: fc1 -> midbf ; fused fc2 + LN(H2 + ffn) -> out
    gemm_mfma<128,128,1,true><<<dim3(8,75), blk, 0, stream>>>(h2bf, nullptr, BIG, 256, f1T, 256, fc1_b, nullptr, 1024, 1024, nullptr, midbf, 1024);
    gemm_ln<<<dim3(300), blk, 0, stream>>>(midbf, 1024, f2T, 1024, fc2_b, out,
                                           fin_ln_w, fin_ln_b, out, nullptr, 0);
}